// Round 1
// baseline (331.262 us; speedup 1.0000x reference)
//
#include <hip/hip_runtime.h>
#include <math.h>

#define LL 4096
#define DD 192
#define NN 16
#define RR 12
#define CC 44   // R + 2N
#define KK 2
#define BB 4

__device__ __forceinline__ float fexp2(float x) {
    return __builtin_amdgcn_exp2f(x);
}

// ---------------------------------------------------------------------------
// Kernel 1: x_dbl projection + dt projection + softplus.
//   delta_out[(bk*D + d)*L + l] = softplus(sum_r dtw[k,d,r]*x_dbl[r] + bias[k,d])
//   bc_out[(bk*L + l)*32 + n]   = Bs (n<16) / Cs (n>=16)
// ---------------------------------------------------------------------------
__global__ __launch_bounds__(256) void proj_kernel(
    const float* __restrict__ x,      // (B,K,D,L)
    const float* __restrict__ xpw,    // (K,44,D)
    const float* __restrict__ dtw,    // (K,D,R)
    const float* __restrict__ bias,   // (K,D)
    float* __restrict__ delta_out,    // (B,K,D,L)
    float* __restrict__ bc_out)       // (B,K,L,32)
{
    __shared__ float wT[DD * CC];     // [d][c], row stride 44 floats = 176B (16B-aligned)
    __shared__ float dtws[DD * RR];   // [d][r], row stride 48B
    __shared__ float bias_s[DD];

    const int tid = threadIdx.x;
    const int bk  = blockIdx.y;       // b*K + k
    const int k   = bk & (KK - 1);

    // Stage weights (transpose xpw slice into [d][c]).
    for (int i = tid; i < DD * CC; i += 256) {
        int c = i / DD, d = i - c * DD;
        wT[d * CC + c] = xpw[k * (CC * DD) + i];
    }
    for (int i = tid; i < DD * RR; i += 256)
        dtws[i] = dtw[k * (DD * RR) + i];
    if (tid < DD) bias_s[tid] = bias[k * DD + tid];
    __syncthreads();

    const int l = blockIdx.x * 256 + tid;
    const float* xr = x + (size_t)bk * DD * LL + l;

    float acc[CC];
    #pragma unroll
    for (int c = 0; c < CC; c++) acc[c] = 0.f;

    for (int d = 0; d < DD; d++) {
        float xv = xr[(size_t)d * LL];            // coalesced across lanes
        const float4* wrow = (const float4*)(&wT[d * CC]);  // uniform addr: LDS broadcast
        #pragma unroll
        for (int c4 = 0; c4 < CC / 4; c4++) {
            float4 w = wrow[c4];
            acc[c4 * 4 + 0] += w.x * xv;
            acc[c4 * 4 + 1] += w.y * xv;
            acc[c4 * 4 + 2] += w.z * xv;
            acc[c4 * 4 + 3] += w.w * xv;
        }
    }

    // Write Bs/Cs interleaved: 32 consecutive floats per l.
    float4* bco = (float4*)(bc_out + ((size_t)bk * LL + l) * 32);
    #pragma unroll
    for (int j = 0; j < 8; j++) {
        float4 v;
        v.x = acc[RR + j * 4 + 0];
        v.y = acc[RR + j * 4 + 1];
        v.z = acc[RR + j * 4 + 2];
        v.w = acc[RR + j * 4 + 3];
        bco[j] = v;
    }

    // dt projection + softplus, one d at a time (stores coalesced across lanes).
    float* dro = delta_out + (size_t)bk * DD * LL + l;
    for (int d = 0; d < DD; d++) {
        const float4* dw = (const float4*)(&dtws[d * RR]);
        float4 w0 = dw[0], w1 = dw[1], w2 = dw[2];
        float z = bias_s[d];
        z += w0.x * acc[0] + w0.y * acc[1] + w0.z * acc[2]  + w0.w * acc[3];
        z += w1.x * acc[4] + w1.y * acc[5] + w1.z * acc[6]  + w1.w * acc[7];
        z += w2.x * acc[8] + w2.y * acc[9] + w2.z * acc[10] + w2.w * acc[11];
        // stable softplus
        float sp = fmaxf(z, 0.f) + log1pf(__expf(-fabsf(z)));
        dro[(size_t)d * LL] = sp;
    }
}

// ---------------------------------------------------------------------------
// Kernel 2: chunked parallel scan. One block per (b,k,d) row; thread t owns
// timesteps [16t, 16t+16) holding all N=16 states in registers.
//   h[l] = exp(delta*A_n) * h[l-1] + delta*x*Bs[n,l];  y = sum_n h*Cs + Ds*x
// Chunk A-product = exp2(An2 * sum_delta)  -> scalar prefix sum of sum_delta,
// B-side scanned Hillis-Steele with A-weights recomputed from cum diffs.
// ---------------------------------------------------------------------------
__global__ __launch_bounds__(256) void scan_kernel(
    const float* __restrict__ x,        // (B,K,D,L)
    const float* __restrict__ delta_in, // (B,K,D,L)
    const float* __restrict__ bc,       // (B,K,L,32)
    const float* __restrict__ A_logs,   // (K*D, N)
    const float* __restrict__ Ds,       // (K*D)
    float* __restrict__ out)            // (B,K,D,L)
{
    __shared__ float delta_s[LL + LL / 16];  // swizzle idx + (idx>>4): stride-17 reads
    __shared__ float x_s[LL + LL / 16];
    __shared__ float Bp[NN][257];
    __shared__ float cum[256];

    const int tid = threadIdx.x;
    const int row = blockIdx.x;          // (b*K + k)*D + d
    const int bk  = row / DD;
    const int d   = row - bk * DD;
    const int k   = bk & (KK - 1);
    const int kd  = k * DD + d;

    const float* drow = delta_in + (size_t)row * LL;
    const float* xrow = x + (size_t)row * LL;

    // Coalesced staging into swizzled LDS.
    for (int i = 0; i < 16; i++) {
        int idx = i * 256 + tid;
        float dv = drow[idx];
        float xv = xrow[idx];
        delta_s[idx + (idx >> 4)] = dv;
        x_s[idx + (idx >> 4)] = xv;
    }

    float An2[NN];  // A_n * log2(e)
    #pragma unroll
    for (int n = 0; n < NN; n++)
        An2[n] = -__expf(A_logs[kd * NN + n]) * 1.44269504f;
    const float Dval = Ds[kd];
    __syncthreads();

    const float4* bc4 = (const float4*)(bc + (size_t)bk * LL * 32);
    const int lb = tid * 16;

    // ---- Pass 1: per-chunk sum_delta and B_run ----
    float Brun[NN];
    #pragma unroll
    for (int n = 0; n < NN; n++) Brun[n] = 0.f;
    float sd = 0.f;

    for (int i = 0; i < 16; i++) {
        int l = lb + i;
        int si = 17 * tid + i;
        float dlt = delta_s[si];
        float dx = dlt * x_s[si];
        sd += dlt;
        float Bsv[NN];
        ((float4*)Bsv)[0] = bc4[l * 8 + 0];
        ((float4*)Bsv)[1] = bc4[l * 8 + 1];
        ((float4*)Bsv)[2] = bc4[l * 8 + 2];
        ((float4*)Bsv)[3] = bc4[l * 8 + 3];
        #pragma unroll
        for (int n = 0; n < NN; n++) {
            float a = fexp2(An2[n] * dlt);
            Brun[n] = a * Brun[n] + dx * Bsv[n];
        }
    }

    cum[tid] = sd;
    #pragma unroll
    for (int n = 0; n < NN; n++) Bp[n][tid] = Brun[n];
    __syncthreads();

    // ---- Scalar inclusive prefix sum of sum_delta ----
    for (int o = 1; o < 256; o <<= 1) {
        float v = (tid >= o) ? cum[tid - o] : 0.f;
        __syncthreads();
        cum[tid] += v;
        __syncthreads();
    }
    const float cum_t = cum[tid];

    // ---- Hillis-Steele inclusive scan of B (16-wide payload) ----
    for (int o = 1; o < 256; o <<= 1) {
        float bprev[NN];
        float cprev = 0.f;
        if (tid >= o) {
            cprev = cum[tid - o];
            #pragma unroll
            for (int n = 0; n < NN; n++) bprev[n] = Bp[n][tid - o];
        }
        __syncthreads();
        if (tid >= o) {
            float cd = cum_t - cprev;  // sum of delta over (tid-o, tid]
            #pragma unroll
            for (int n = 0; n < NN; n++) {
                float w = fexp2(An2[n] * cd);  // A-product over own segment
                Brun[n] = w * bprev[n] + Brun[n];
                Bp[n][tid] = Brun[n];
            }
        }
        __syncthreads();
    }

    // Exclusive prefix = inclusive of previous chunk.
    float h[NN];
    #pragma unroll
    for (int n = 0; n < NN; n++) h[n] = (tid > 0) ? Bp[n][tid - 1] : 0.f;

    // ---- Pass 2: replay with prefix, emit y ----
    float yout[16];
    for (int i = 0; i < 16; i++) {
        int l = lb + i;
        int si = 17 * tid + i;
        float dlt = delta_s[si];
        float xv = x_s[si];
        float dx = dlt * xv;
        float Bsv[NN], Csv[NN];
        ((float4*)Bsv)[0] = bc4[l * 8 + 0];
        ((float4*)Bsv)[1] = bc4[l * 8 + 1];
        ((float4*)Bsv)[2] = bc4[l * 8 + 2];
        ((float4*)Bsv)[3] = bc4[l * 8 + 3];
        ((float4*)Csv)[0] = bc4[l * 8 + 4];
        ((float4*)Csv)[1] = bc4[l * 8 + 5];
        ((float4*)Csv)[2] = bc4[l * 8 + 6];
        ((float4*)Csv)[3] = bc4[l * 8 + 7];
        float y = Dval * xv;
        #pragma unroll
        for (int n = 0; n < NN; n++) {
            float a = fexp2(An2[n] * dlt);
            h[n] = a * h[n] + dx * Bsv[n];
            y += h[n] * Csv[n];
        }
        yout[i] = y;
    }

    float4* yr = (float4*)(out + (size_t)row * LL + lb);
    #pragma unroll
    for (int j = 0; j < 4; j++) {
        float4 v;
        v.x = yout[j * 4 + 0];
        v.y = yout[j * 4 + 1];
        v.z = yout[j * 4 + 2];
        v.w = yout[j * 4 + 3];
        yr[j] = v;
    }
}

extern "C" void kernel_launch(void* const* d_in, const int* in_sizes, int n_in,
                              void* d_out, int out_size, void* d_ws, size_t ws_size,
                              hipStream_t stream) {
    const float* x      = (const float*)d_in[0];
    const float* xpw    = (const float*)d_in[1];
    const float* dtw    = (const float*)d_in[2];
    const float* bias   = (const float*)d_in[3];
    const float* A_logs = (const float*)d_in[4];
    const float* Ds     = (const float*)d_in[5];
    float* out = (float*)d_out;

    float* delta_ws = (float*)d_ws;                         // B*K*D*L floats = 25.2 MB
    float* bc_ws = delta_ws + (size_t)BB * KK * DD * LL;    // B*K*L*32 floats = 4.2 MB

    dim3 g1(LL / 256, BB * KK);
    proj_kernel<<<g1, 256, 0, stream>>>(x, xpw, dtw, bias, delta_ws, bc_ws);
    scan_kernel<<<BB * KK * DD, 256, 0, stream>>>(x, delta_ws, bc_ws, A_logs, Ds, out);
}

// Round 2
// 215.585 us; speedup vs baseline: 1.5366x; 1.5366x over previous
//
#include <hip/hip_runtime.h>
#include <math.h>

#define LL 4096
#define DD 192
#define NN 16
#define RR 12
#define CC 44   // R + 2N
#define KK 2
#define BB 4
#define DPG 48  // d's per d-group in proj (192/4)

__device__ __forceinline__ float fexp2(float x) {
    return __builtin_amdgcn_exp2f(x);
}

// ---------------------------------------------------------------------------
// Kernel 1: projection. Grid (L/64, B*K), 256 thr = 64 l-lanes x 4 d-groups.
// Weights read via wave-uniform global indices -> scalar loads.
// Outputs:
//   delta[(bk*D+d)*L + l]  (coalesced stores)
//   Bs_perm/Cs_perm [bk][i=l&63][lg=l>>6][16 floats]  -- scan-native layout
// ---------------------------------------------------------------------------
__global__ __launch_bounds__(256) void proj_kernel(
    const float* __restrict__ x,      // (B,K,D,L)
    const float* __restrict__ xpw,    // (K,44,D)
    const float* __restrict__ dtw,    // (K,D,R)
    const float* __restrict__ bias,   // (K,D)
    float* __restrict__ delta_out,    // (B,K,D,L)
    float* __restrict__ bs_perm,      // (B*K, 64, 64, 16)
    float* __restrict__ cs_perm)      // (B*K, 64, 64, 16)
{
    __shared__ float accs[CC * 4 * 65];   // [c][dg][tl], tl-row padded to 65
    __shared__ float accsum[RR * 65];     // summed acc for c<12 (dt projection)

    const int tid = threadIdx.x;
    const int tl  = tid & 63;     // l within tile
    const int dg  = tid >> 6;     // d-group 0..3
    const int bk  = blockIdx.y;
    const int k   = bk & (KK - 1);
    const int lbase = blockIdx.x * 64;
    const int l = lbase + tl;

    const float* xr = x + (size_t)bk * DD * LL + l;
    const float* wk = xpw + k * (CC * DD);   // wave-uniform base

    // Phase A: partial c-accumulation over this d-group's 48 d's.
    float acc[CC];
    #pragma unroll
    for (int c = 0; c < CC; c++) acc[c] = 0.f;

    for (int dd = 0; dd < DPG; dd++) {
        const int d = dg * DPG + dd;
        const float xv = xr[(size_t)d * LL];           // coalesced over tl
        const float* wd = wk + d;                      // uniform
        #pragma unroll
        for (int c = 0; c < CC; c++)
            acc[c] += wd[c * DD] * xv;                 // s_load + v_fmac
    }

    #pragma unroll
    for (int c = 0; c < CC; c++)
        accs[(c * 4 + dg) * 65 + tl] = acc[c];
    __syncthreads();

    // Phase B1: accsum for c<12 (needed by dt projection). 768 sums.
    #pragma unroll
    for (int j2 = 0; j2 < 3; j2++) {
        int ii = j2 * 256 + tid;          // < 768
        int c = ii >> 6, t2 = ii & 63;
        float s = accs[(c * 4 + 0) * 65 + t2] + accs[(c * 4 + 1) * 65 + t2]
                + accs[(c * 4 + 2) * 65 + t2] + accs[(c * 4 + 3) * 65 + t2];
        accsum[c * 65 + t2] = s;
    }

    // Phase B2: Bs/Cs stores in permuted layout. 512 float4s per tile; 2/thread.
    #pragma unroll
    for (int q = 0; q < 2; q++) {
        int s = q * 256 + tid;            // 0..511
        int arr = s >> 8;                 // 0=Bs, 1=Cs
        int r = s & 255;
        int t2 = r >> 2;                  // which l in tile
        int j = r & 3;                    // which float4 of the 16 states
        float4 v;
        float* vp = (float*)&v;
        #pragma unroll
        for (int jj = 0; jj < 4; jj++) {
            int c = RR + arr * NN + j * 4 + jj;
            vp[jj] = accs[(c * 4 + 0) * 65 + t2] + accs[(c * 4 + 1) * 65 + t2]
                   + accs[(c * 4 + 2) * 65 + t2] + accs[(c * 4 + 3) * 65 + t2];
        }
        // target slot: i = t2 (tile is 64-aligned), lg = blockIdx.x
        size_t f4idx = (((size_t)bk * 64 + t2) * 64 + blockIdx.x) * 4 + j;
        float4* dst = (float4*)(arr ? cs_perm : bs_perm);
        dst[f4idx] = v;
    }
    __syncthreads();

    // Phase C: dt projection + softplus for this d-group's 48 d's.
    const float* dtk = dtw + k * (DD * RR);
    const float* bik = bias + k * DD;
    float* dro = delta_out + (size_t)bk * DD * LL + l;
    for (int dd = 0; dd < DPG; dd++) {
        const int d = dg * DPG + dd;
        const float* dwr = dtk + d * RR;               // uniform
        float z = bik[d];
        #pragma unroll
        for (int r = 0; r < RR; r++)
            z += dwr[r] * accsum[r * 65 + tl];
        float sp = fmaxf(z, 0.f) + log1pf(__expf(-fabsf(z)));
        dro[(size_t)d * LL] = sp;                      // coalesced over tl
    }
}

// ---------------------------------------------------------------------------
// Kernel 2: chunked scan. One block per (b,k,d) row. 256 thr = 64 chunks (lg)
// x 4 n-quads (ng). Thread owns l in [lg*64, lg*64+64), states 4ng..4ng+3.
// bc loads are float4 at idx i*256+tid -> fully coalesced.
// ---------------------------------------------------------------------------
__global__ __launch_bounds__(256) void scan_kernel(
    const float* __restrict__ x,        // (B,K,D,L)
    const float* __restrict__ delta_in, // (B,K,D,L)
    const float* __restrict__ bs_perm,  // (B*K, 64, 64, 16)
    const float* __restrict__ cs_perm,  // (B*K, 64, 64, 16)
    const float* __restrict__ A_logs,   // (K*D, N)
    const float* __restrict__ Ds,       // (K*D)
    float* __restrict__ out)            // (B,K,D,L)
{
    __shared__ float delta_s[LL + 63];  // chunk lg at [lg*65, lg*65+64)
    __shared__ float x_s[LL + 63];
    __shared__ float Bp[64 * 20];       // [lg][16 states + pad4]
    __shared__ float cum[64];

    const int tid = threadIdx.x;
    const int ng  = tid & 3;
    const int lg  = tid >> 2;
    const int row = blockIdx.x;
    const int bk  = row / DD;
    const int d   = row - bk * DD;
    const int k   = bk & (KK - 1);
    const int kd  = k * DD + d;

    const float* drow = delta_in + (size_t)row * LL;
    const float* xrow = x + (size_t)row * LL;

    #pragma unroll
    for (int i = 0; i < 16; i++) {
        int idx = i * 256 + tid;
        delta_s[idx + (idx >> 6)] = drow[idx];
        x_s[idx + (idx >> 6)] = xrow[idx];
    }

    float An2[4];
    #pragma unroll
    for (int j = 0; j < 4; j++)
        An2[j] = -__expf(A_logs[kd * NN + 4 * ng + j]) * 1.44269504f;
    const float Dval = Ds[kd];
    __syncthreads();

    const float4* bs4 = (const float4*)(bs_perm + (size_t)bk * 64 * 64 * NN);
    const float4* cs4 = (const float4*)(cs_perm + (size_t)bk * 64 * 64 * NN);
    const int sbase = lg * 65;

    // ---- Pass 1: per-chunk sum_delta and running B ----
    float Brun[4] = {0.f, 0.f, 0.f, 0.f};
    float sd = 0.f;
    for (int i = 0; i < 64; i++) {
        float dlt = delta_s[sbase + i];
        float dx = dlt * x_s[sbase + i];
        sd += dlt;
        float4 Bsv = bs4[i * 256 + tid];          // coalesced
        const float* bp = (const float*)&Bsv;
        #pragma unroll
        for (int j = 0; j < 4; j++) {
            float a = fexp2(An2[j] * dlt);
            Brun[j] = a * Brun[j] + dx * bp[j];
        }
    }

    if (ng == 0) cum[lg] = sd;
    ((float4*)(Bp + lg * 20 + 4 * ng))[0] = *(float4*)Brun;
    __syncthreads();

    // ---- Scalar prefix sum over 64 chunk sum_deltas ----
    #pragma unroll
    for (int o = 1; o < 64; o <<= 1) {
        float v = 0.f;
        if (tid < 64 && tid >= o) v = cum[tid - o];
        __syncthreads();
        if (tid < 64 && tid >= o) cum[tid] += v;
        __syncthreads();
    }
    const float cum_t = cum[lg];

    // ---- Hillis-Steele scan of B over 64 chunks (float4 payload) ----
    #pragma unroll
    for (int o = 1; o < 64; o <<= 1) {
        float4 bprev;
        float cprev = 0.f;
        const bool valid = (lg >= o);
        if (valid) {
            cprev = cum[lg - o];
            bprev = ((float4*)(Bp + (lg - o) * 20 + 4 * ng))[0];
        }
        __syncthreads();
        if (valid) {
            float cd = cum_t - cprev;
            const float* bp = (const float*)&bprev;
            #pragma unroll
            for (int j = 0; j < 4; j++) {
                float w = fexp2(An2[j] * cd);
                Brun[j] = w * bp[j] + Brun[j];
            }
            ((float4*)(Bp + lg * 20 + 4 * ng))[0] = *(float4*)Brun;
        }
        __syncthreads();
    }

    // Exclusive prefix for this chunk.
    float h[4] = {0.f, 0.f, 0.f, 0.f};
    if (lg > 0) {
        float4 hp = ((float4*)(Bp + (lg - 1) * 20 + 4 * ng))[0];
        h[0] = hp.x; h[1] = hp.y; h[2] = hp.z; h[3] = hp.w;
    }

    // ---- Pass 2: replay, reduce y over the n-quad, stage into x_s ----
    for (int i = 0; i < 64; i++) {
        int si = sbase + i;
        float dlt = delta_s[si];
        float xv = x_s[si];
        float dx = dlt * xv;
        float4 Bsv = bs4[i * 256 + tid];
        float4 Csv = cs4[i * 256 + tid];
        const float* bp = (const float*)&Bsv;
        const float* cp = (const float*)&Csv;
        float yp = 0.f;
        #pragma unroll
        for (int j = 0; j < 4; j++) {
            float a = fexp2(An2[j] * dlt);
            h[j] = a * h[j] + dx * bp[j];
            yp += h[j] * cp[j];
        }
        yp += __shfl_xor(yp, 1, 64);
        yp += __shfl_xor(yp, 2, 64);
        if (ng == 0) x_s[si] = yp + Dval * xv;   // intra-wave: reads precede write
    }
    __syncthreads();

    float* orow = out + (size_t)row * LL;
    #pragma unroll
    for (int i = 0; i < 16; i++) {
        int idx = i * 256 + tid;
        orow[idx] = x_s[idx + (idx >> 6)];       // coalesced
    }
}

extern "C" void kernel_launch(void* const* d_in, const int* in_sizes, int n_in,
                              void* d_out, int out_size, void* d_ws, size_t ws_size,
                              hipStream_t stream) {
    const float* x      = (const float*)d_in[0];
    const float* xpw    = (const float*)d_in[1];
    const float* dtw    = (const float*)d_in[2];
    const float* bias   = (const float*)d_in[3];
    const float* A_logs = (const float*)d_in[4];
    const float* Ds     = (const float*)d_in[5];
    float* out = (float*)d_out;

    float* delta_ws = (float*)d_ws;                          // 6291456 floats
    float* bs_ws = delta_ws + (size_t)BB * KK * DD * LL;     // 524288 floats
    float* cs_ws = bs_ws + (size_t)BB * KK * 64 * 64 * NN;   // 524288 floats

    dim3 g1(LL / 64, BB * KK);
    proj_kernel<<<g1, 256, 0, stream>>>(x, xpw, dtw, bias, delta_ws, bs_ws, cs_ws);
    scan_kernel<<<BB * KK * DD, 256, 0, stream>>>(x, delta_ws, bs_ws, cs_ws,
                                                  A_logs, Ds, out);
}